// Round 8
// baseline (230.556 us; speedup 1.0000x reference)
//
#include <hip/hip_runtime.h>
#include <math.h>

#define A_N 64
#define B_N 4096
#define D_N 50
#define H_N 192
#define O_N 3

typedef __attribute__((ext_vector_type(8))) __bf16 bf16x8;
typedef __attribute__((ext_vector_type(4))) __bf16 bf16x4;
typedef __attribute__((ext_vector_type(4))) float f32x4;
typedef __attribute__((ext_vector_type(2))) float f32x2;

// ws layout (bf16 elems), frag-packed: frag elem (lane,j) = W[nt*16+(lane&15)][ks*32+(lane>>4)*8+j]
#define W1_OFF   0          // [A][12 nt][2 ks][512]   K=64 (padded from 50)
#define S1_OFF   786432
#define W2_OFF   1572864    // [A][12 nt][6 ks][512]   K=192
#define S2_OFF   3932160
#define W3_OFF   6291456
#define OW_OFF   8650752    // [A][6 ks][512]          N=16 (padded from 3), K=192
#define WS_ELEMS 8847360    // *2 B = 17.7 MB of d_ws

#if __has_builtin(__builtin_amdgcn_rcpf)
#define FRCP(x) __builtin_amdgcn_rcpf(x)
#else
#define FRCP(x) (1.0f / (x))
#endif
#if __has_builtin(__builtin_amdgcn_exp2f)
#define FEXP2(x) __builtin_amdgcn_exp2f(x)
#else
#define FEXP2(x) exp2f(x)
#endif

// ---- packed-f32 helpers (CDNA v_pk_fma_f32 / v_pk_mul_f32 / v_pk_add_f32) ----
static __device__ __forceinline__ f32x2 f2(float v)            { f32x2 r; r[0] = v;    r[1] = v;    return r; }
static __device__ __forceinline__ f32x2 lo2(f32x4 v)           { f32x2 r; r[0] = v[0]; r[1] = v[1]; return r; }
static __device__ __forceinline__ f32x2 hi2(f32x4 v)           { f32x2 r; r[0] = v[2]; r[1] = v[3]; return r; }
static __device__ __forceinline__ f32x4 cmb(f32x2 a, f32x2 b)  { f32x4 r; r[0] = a[0]; r[1] = a[1]; r[2] = b[0]; r[3] = b[1]; return r; }
static __device__ __forceinline__ f32x2 fma2(f32x2 a, f32x2 b, f32x2 c) {
#if __has_builtin(__builtin_elementwise_fma)
    return __builtin_elementwise_fma(a, b, c);
#else
    f32x2 r; r[0] = fmaf(a[0], b[0], c[0]); r[1] = fmaf(a[1], b[1], c[1]); return r;
#endif
}
static __device__ __forceinline__ f32x2 abs2(f32x2 v) {
#if __has_builtin(__builtin_elementwise_abs)
    return __builtin_elementwise_abs(v);
#else
    f32x2 r; r[0] = fabsf(v[0]); r[1] = fabsf(v[1]); return r;
#endif
}

// A&S 7.1.26 erf, packed 2-wide. Sign-free: x*erf(x/sqrt2) = |x|*erf(|x|/sqrt2)
// (erf odd) -> gelu = 0.7071*(t + |t|*er), no cmp/cndmask. (Round-7 verified:
// absmax identical 1.525879e-05, -11% wall.)
__device__ __forceinline__ f32x2 gelu2(f32x2 xx) {
    const f32x2 chs = f2(0.70710678118654752440f);
    f32x2 t  = xx * chs;
    f32x2 at = abs2(t);
    f32x2 d  = fma2(at, f2(0.3275911f), f2(1.0f));
    f32x2 k; k[0] = FRCP(d[0]); k[1] = FRCP(d[1]);
    f32x2 p  = fma2(k, f2(1.061405429f), f2(-1.453152027f));
    p = fma2(k, p, f2(1.421413741f));
    p = fma2(k, p, f2(-0.284496736f));
    p = fma2(k, p, f2(0.254829592f));
    p = p * k;
    f32x2 t2 = t * t;
    f32x2 a2 = t2 * f2(-1.44269504088896340736f);
    f32x2 e; e[0] = FEXP2(a2[0]); e[1] = FEXP2(a2[1]);
    f32x2 er = fma2(-p, e, f2(1.0f));
    f32x2 r  = fma2(at, er, t);
    return r * chs;
}

// Prep v3 (HW-validated). Round-1 lesson: prep is ~8 us of BW-bound work; the ~78 us
// total-vs-srek gap is FIXED harness overhead (noisy +-15us). Do NOT delete prep.
__global__ __launch_bounds__(256)
void prep_kernel(const float* __restrict__ w1, const float* __restrict__ s1,
                 const float* __restrict__ w2, const float* __restrict__ s2,
                 const float* __restrict__ w3, const float* __restrict__ ow,
                 __bf16* __restrict__ ws) {
    __shared__ __bf16 T[192 * 72];   // sec A uses [32][200] = 6400 of it
    const int b   = blockIdx.x;
    const int tid = threadIdx.x;

    if (b < 1152) {
        int m  = b / 384;                 // 0=w2 1=s2 2=w3
        int r  = b % 384;
        int a  = r / 6;
        int rc = r % 6;                   // 32-row chunk
        const float* src = ((m == 0) ? w2 : (m == 1) ? s2 : w3) + (size_t)a * 36864;
        __bf16* dst = ws + ((m == 0) ? W2_OFF : (m == 1) ? S2_OFF : W3_OFF) + (size_t)a * 36864;
        #pragma unroll
        for (int i = 0; i < 6; ++i) {                 // 1536 float4 = 32 rows x 192 cols
            int f4 = i * 256 + tid;
            int row = f4 / 48, kc = (f4 % 48) * 4;
            f32x4 v = *(const f32x4*)(src + (size_t)(rc * 32 + row) * 192 + kc);
            bf16x4 o;
            #pragma unroll
            for (int j = 0; j < 4; ++j) o[j] = (__bf16)v[j];
            *(bf16x4*)(T + row * 200 + kc) = o;       // pitch 200: 2-way max
        }
        __syncthreads();
        #pragma unroll
        for (int i = 0; i < 3; ++i) {                 // 768 frag-rows (2 nt x 6 ks x 64)
            int fr = i * 256 + tid;
            int f = fr >> 6, lane = fr & 63;
            int ntl = f / 6, ks = f % 6;
            int n = ntl * 16 + (lane & 15), k = ks * 32 + (lane >> 4) * 8;
            bf16x8 v = *(const bf16x8*)(T + n * 200 + k);
            *(bf16x8*)(dst + ((size_t)(rc * 2 + ntl) * 6 + ks) * 512 + lane * 8) = v;
        }
    } else if (b < 1280) {
        int r = b - 1152; int m = r >> 6; int a = r & 63;
        const float* src = (m ? s1 : w1) + (size_t)a * 9600;
        __bf16* dst = ws + (m ? S1_OFF : W1_OFF) + (size_t)a * 12288;
        for (int e = tid; e < 192 * 72; e += 256) T[e] = (__bf16)0.f;
        __syncthreads();
        for (int e = tid; e < 9600; e += 256) {
            int row = e / 50, k = e - row * 50;
            T[row * 72 + k] = (__bf16)src[e];
        }
        __syncthreads();
        #pragma unroll
        for (int i = 0; i < 6; ++i) {                 // 1536 frag-rows (12 nt x 2 ks x 64)
            int fr = i * 256 + tid;
            int f = fr >> 6, lane = fr & 63;
            int nt = f >> 1, ks = f & 1;
            int n = nt * 16 + (lane & 15), k = ks * 32 + (lane >> 4) * 8;
            bf16x8 v = *(const bf16x8*)(T + n * 72 + k);
            *(bf16x8*)(dst + (size_t)(nt * 2 + ks) * 512 + lane * 8) = v;
        }
    } else {
        int r = b - 1280;
        #pragma unroll
        for (int i = 0; i < 8; ++i) {                 // 24576 frag-rows total
            int fr = (r * 8 + i) * 256 + tid;
            int a = fr / 384, rem = fr - a * 384;
            int ks = rem >> 6, lane = rem & 63;
            int n = lane & 15, k = ks * 32 + (lane >> 4) * 8;
            bf16x8 v;
            if (n < O_N) {
                const float* p = ow + ((size_t)a * O_N + n) * H_N + k;
                f32x4 f0 = *(const f32x4*)p, f1 = *(const f32x4*)(p + 4);
                #pragma unroll
                for (int j = 0; j < 4; ++j) { v[j] = (__bf16)f0[j]; v[4 + j] = (__bf16)f1[j]; }
            } else {
                #pragma unroll
                for (int j = 0; j < 8; ++j) v[j] = (__bf16)0.f;
            }
            *(bf16x8*)(ws + OW_OFF + (size_t)a * 3072 + ks * 512 + lane * 8) = v;
        }
    }
}

// Operand-swapped MFMA: weights = A, activations = B.
// D: col(weight-col) = quad*4+reg, row(batch-row) = lane&15.
#define MFMA(a, b, c) __builtin_amdgcn_mfma_f32_16x16x32_bf16((a), (b), (c), 0, 0, 0)

// ROUND 8: round-7 base (131.7 us; packed-f32 gelu, ping-pong LDS, (256,3)) + two
// more VALU cuts. Evidence: wall tracks VALU-busy ~1:1 (R7: -8us VALU -> -16us wall);
// MFMA-busy ~31us is already near the 28us MFMA roofline.
//  (a) PING-PONG WEIGHT REGS (nxA/nxB, 2-unrolled loops): kills the per-ks nxt->cw
//      copies (~480 v_mov/thread, ~11% of VALU). Peak reg footprint unchanged (48).
//  (b) VECTORIZED x_norm STAGING: 2 bf16x8 rows/thread (one ds_write_b128 each)
//      instead of 16 scalar elems/writes; same per-element fmaf+cvt (bit-identical).
// Lessons kept: no (256,4) [spills], no bias-C-init, no setprio, prep stays.
__global__ __launch_bounds__(256, 3)
void srek_mfma(const float* __restrict__ x,
               const float* __restrict__ inw, const float* __restrict__ inb,
               const float* __restrict__ b1,  const float* __restrict__ b2,
               const float* __restrict__ b3,  const float* __restrict__ s1b,
               const float* __restrict__ s2b, const float* __restrict__ hnw,
               const float* __restrict__ hnb, const float* __restrict__ ob,
               const __bf16* __restrict__ ws, float* __restrict__ out) {
    __shared__ __bf16 bufA[24 * 512];  // x_norm (8x512 used) -> h2 (24 KB)
    __shared__ __bf16 bufB[24 * 512];  // h1 -> h3            (24 KB)

    const int bid  = blockIdx.x;
    const int slot = bid >> 3;
    const int tile = slot & 63;
    const int a    = ((bid & 7) << 3) | (slot >> 6);   // agent pinned to XCD
    const int row0 = tile * 64;

    const int tid  = threadIdx.x;
    const int lane = tid & 63;
    const int wv   = tid >> 6;     // col-quarter
    const int ln   = lane & 15;
    const int quad = lane >> 4;
    const int aH   = a * H_N;
    const int c0   = wv * 48;
    const int l8   = lane * 8;
    const int f3   = wv * 3;       // this wave's nt base (3 disjoint col-tiles)

    const __bf16* W1 = ws + W1_OFF + (size_t)a * 12288;
    const __bf16* S1 = ws + S1_OFF + (size_t)a * 12288;
    const __bf16* W2 = ws + W2_OFF + (size_t)a * 36864;
    const __bf16* S2 = ws + S2_OFF + (size_t)a * 36864;
    const __bf16* W3 = ws + W3_OFF + (size_t)a * 36864;
    const __bf16* OWp= ws + OW_OFF + (size_t)a * 3072;

    bf16x8 nxA[6], nxB[6];         // ping-pong weight frags (W in [0..2], S in [3..5])
    f32x4 accT[12], accS[12], h2f[12];
    const f32x4 fzero = {0.f, 0.f, 0.f, 0.f};

    // prefetch L1 ks0 -> nxA
    #pragma unroll
    for (int t = 0; t < 3; ++t) {
        nxA[t]     = *(const bf16x8*)(W1 + ((f3 + t) * 2 + 0) * 512 + l8);
        nxA[3 + t] = *(const bf16x8*)(S1 + ((f3 + t) * 2 + 0) * 512 + l8);
    }

    // x_norm -> bufA frag-major [mt4][ks2][512]: 2 frag-rows/thread, b128 writes
    #pragma unroll
    for (int i = 0; i < 2; ++i) {
        int fr  = i * 256 + tid;                       // frag-row = e>>3 of old code
        int lnn = fr & 15, qd = (fr >> 4) & 3, kss = (fr >> 6) & 1, mtt = (fr >> 7) & 3;
        int r   = mtt * 16 + lnn;
        int k0  = kss * 32 + qd * 8;
        const float* xr = x + (size_t)(row0 + r) * D_N;
        bf16x8 v;
        #pragma unroll
        for (int j = 0; j < 8; ++j) {
            int k = k0 + j;
            float f = 0.f;
            if (k < D_N) f = fmaf(xr[k], inw[a * D_N + k], inb[a * D_N + k]);
            v[j] = (__bf16)f;
        }
        *(bf16x8*)(bufA + fr * 8) = v;
    }

    // first=true: C-operand is fzero (replaces bulk acc zeroing, bit-identical)
    auto compute_dual_first = [&](const __bf16* As, int KS, int ks,
                                  const bf16x8* cw, const bf16x8* cs) {
        #pragma unroll
        for (int mt = 0; mt < 4; ++mt) {
            bf16x8 av = *(const bf16x8*)(As + (mt * KS + ks) * 512 + l8);
            #pragma unroll
            for (int t = 0; t < 3; ++t) {
                accT[mt * 3 + t] = MFMA(cw[t], av, fzero);
                accS[mt * 3 + t] = MFMA(cs[t], av, fzero);
            }
        }
    };
    auto compute_dual = [&](const __bf16* As, int KS, int ks,
                            const bf16x8* cw, const bf16x8* cs) {
        #pragma unroll
        for (int mt = 0; mt < 4; ++mt) {
            bf16x8 av = *(const bf16x8*)(As + (mt * KS + ks) * 512 + l8);
            #pragma unroll
            for (int t = 0; t < 3; ++t) {
                accT[mt * 3 + t] = MFMA(cw[t], av, accT[mt * 3 + t]);
                accS[mt * 3 + t] = MFMA(cs[t], av, accS[mt * 3 + t]);
            }
        }
    };
    auto compute_single_first = [&](const __bf16* As, int ks, const bf16x8* cw) {
        #pragma unroll
        for (int mt = 0; mt < 4; ++mt) {
            bf16x8 av = *(const bf16x8*)(As + (mt * 6 + ks) * 512 + l8);
            #pragma unroll
            for (int t = 0; t < 3; ++t)
                accT[mt * 3 + t] = MFMA(cw[t], av, fzero);
        }
    };
    auto compute_single = [&](const __bf16* As, int ks, const bf16x8* cw) {
        #pragma unroll
        for (int mt = 0; mt < 4; ++mt) {
            bf16x8 av = *(const bf16x8*)(As + (mt * 6 + ks) * 512 + l8);
            #pragma unroll
            for (int t = 0; t < 3; ++t)
                accT[mt * 3 + t] = MFMA(cw[t], av, accT[mt * 3 + t]);
        }
    };
    // store 12 f32x4 (C-layout) into dst frag-major as bf16
    auto store_fragmajor = [&](__bf16* dst, const f32x4* src) {
        #pragma unroll
        for (int t = 0; t < 3; ++t) {
            int ks2 = (3 * wv + t) >> 1;                       // (48wv+16t)>>5
            int qp  = (6 * wv + 2 * t + (quad >> 1)) & 3;      // chunk within frag
            int off = (qp * 16 + ln) * 8 + (quad & 1) * 4;     // 8B-aligned
            #pragma unroll
            for (int mt = 0; mt < 4; ++mt) {
                bf16x4 o;
                #pragma unroll
                for (int rg = 0; rg < 4; ++rg) o[rg] = (__bf16)src[mt * 3 + t][rg];
                *(bf16x4*)(dst + (mt * 6 + ks2) * 512 + off) = o;
            }
        }
    };
    // h2f = gelu(accT + bias) + accS + sbias   (packed 2-wide; order = legacy)
    auto ep_skip = [&](const float* bias, const float* sbias) {
        #pragma unroll
        for (int t = 0; t < 3; ++t) {
            int colb = c0 + t * 16 + quad * 4;
            f32x4 bb = *(const f32x4*)(bias  + aH + colb);
            f32x4 sb = *(const f32x4*)(sbias + aH + colb);
            f32x2 bbl = lo2(bb), bbh = hi2(bb), sbl = lo2(sb), sbh = hi2(sb);
            #pragma unroll
            for (int mt = 0; mt < 4; ++mt) {
                int i = mt * 3 + t;
                f32x2 g0 = gelu2(lo2(accT[i]) + bbl);
                f32x2 g1 = gelu2(hi2(accT[i]) + bbh);
                f32x2 h0 = (g0 + lo2(accS[i])) + sbl;
                f32x2 h1 = (g1 + hi2(accS[i])) + sbh;
                h2f[i] = cmb(h0, h1);
            }
        }
    };

    __syncthreads();                                   // B1: x_norm (bufA) ready

    // ================= layer1 + skip1 (K=64, 2 chunks; ping-pong) =================
    {
        #pragma unroll
        for (int t = 0; t < 3; ++t) {                  // prefetch L1 ks1 -> nxB
            nxB[t]     = *(const bf16x8*)(W1 + ((f3 + t) * 2 + 1) * 512 + l8);
            nxB[3 + t] = *(const bf16x8*)(S1 + ((f3 + t) * 2 + 1) * 512 + l8);
        }
        compute_dual_first(bufA, 2, 0, nxA, nxA + 3);
        #pragma unroll
        for (int t = 0; t < 3; ++t) {                  // prefetch L2 ks0 -> nxA
            nxA[t]     = *(const bf16x8*)(W2 + ((f3 + t) * 6 + 0) * 512 + l8);
            nxA[3 + t] = *(const bf16x8*)(S2 + ((f3 + t) * 6 + 0) * 512 + l8);
        }
        compute_dual(bufA, 2, 1, nxB, nxB + 3);
    }
    ep_skip(b1, s1b);                                  // h1 (fp32) in h2f
    store_fragmajor(bufB, h2f);
    __syncthreads();                                   // B2: h1 (bufB) ready

    // ================= layer2 + skip2 (K=192, 6 chunks; ping-pong) =================
    #pragma unroll
    for (int kk = 0; kk < 3; ++kk) {
        const int ks0 = 2 * kk, ks1 = 2 * kk + 1;
        #pragma unroll
        for (int t = 0; t < 3; ++t) {                  // prefetch ks1 -> nxB
            nxB[t]     = *(const bf16x8*)(W2 + ((f3 + t) * 6 + ks1) * 512 + l8);
            nxB[3 + t] = *(const bf16x8*)(S2 + ((f3 + t) * 6 + ks1) * 512 + l8);
        }
        if (kk == 0) compute_dual_first(bufB, 6, ks0, nxA, nxA + 3);
        else         compute_dual(bufB, 6, ks0, nxA, nxA + 3);
        if (kk < 2) {
            #pragma unroll
            for (int t = 0; t < 3; ++t) {              // prefetch ks1+1 -> nxA
                nxA[t]     = *(const bf16x8*)(W2 + ((f3 + t) * 6 + ks1 + 1) * 512 + l8);
                nxA[3 + t] = *(const bf16x8*)(S2 + ((f3 + t) * 6 + ks1 + 1) * 512 + l8);
            }
        } else {
            #pragma unroll
            for (int t = 0; t < 3; ++t)                // prefetch L3 ks0 -> nxA
                nxA[t] = *(const bf16x8*)(W3 + ((f3 + t) * 6 + 0) * 512 + l8);
        }
        compute_dual(bufB, 6, ks1, nxB, nxB + 3);
    }
    ep_skip(b2, s2b);                                  // h2 (fp32) in h2f, kept for residual
    // h2 -> bufA (x_norm reads all finished before B2; no extra barrier needed)
    store_fragmajor(bufA, h2f);
    __syncthreads();                                   // B3: h2 (bufA) ready

    // ================= layer3 (K=192; ping-pong) =================
    bf16x8 ow6[6];
    #pragma unroll
    for (int kk = 0; kk < 3; ++kk) {
        const int ks0 = 2 * kk, ks1 = 2 * kk + 1;
        #pragma unroll
        for (int t = 0; t < 3; ++t)                    // prefetch ks1 -> nxB
            nxB[t] = *(const bf16x8*)(W3 + ((f3 + t) * 6 + ks1) * 512 + l8);
        if (kk == 0) compute_single_first(bufA, ks0, nxA);
        else         compute_single(bufA, ks0, nxA);
        if (kk < 2) {
            #pragma unroll
            for (int t = 0; t < 3; ++t)                // prefetch ks1+1 -> nxA
                nxA[t] = *(const bf16x8*)(W3 + ((f3 + t) * 6 + ks1 + 1) * 512 + l8);
        } else {
            #pragma unroll
            for (int kq = 0; kq < 6; ++kq)             // prefetch OW
                ow6[kq] = *(const bf16x8*)(OWp + kq * 512 + l8);
        }
        compute_single(bufA, ks1, nxB);
    }
    // h3 = (accT + b3 + h2)*hnw + hnb   (packed 2-wide; order = legacy)
    #pragma unroll
    for (int t = 0; t < 3; ++t) {
        int colb = c0 + t * 16 + quad * 4;
        f32x4 b3v = *(const f32x4*)(b3  + aH + colb);
        f32x4 nwv = *(const f32x4*)(hnw + aH + colb);
        f32x4 nbv = *(const f32x4*)(hnb + aH + colb);
        #pragma unroll
        for (int mt = 0; mt < 4; ++mt) {
            int i = mt * 3 + t;
            f32x2 s0 = (lo2(accT[i]) + lo2(b3v)) + lo2(h2f[i]);
            f32x2 s1 = (hi2(accT[i]) + hi2(b3v)) + hi2(h2f[i]);
            h2f[i] = cmb(fma2(s0, lo2(nwv), lo2(nbv)),
                         fma2(s1, hi2(nwv), hi2(nbv)));
        }
    }
    // h3 -> bufB (h1 reads all finished before B3; no extra barrier needed)
    store_fragmajor(bufB, h2f);
    __syncthreads();                                   // B4: h3 (bufB) ready

    // ================= output (wave wv = row-mtile wv) =================
    {
        f32x4 acco = fzero;
        #pragma unroll
        for (int ks = 0; ks < 6; ++ks) {
            bf16x8 av = *(const bf16x8*)(bufB + (wv * 6 + ks) * 512 + l8);
            acco = MFMA(ow6[ks], av, acco);
        }
        if (quad == 0) {                               // o = rg (0..2), rows = wv*16+ln
            float* po = out + ((size_t)a * B_N + row0 + wv * 16 + ln) * O_N;
            po[0] = acco[0] + ob[a * O_N + 0];
            po[1] = acco[1] + ob[a * O_N + 1];
            po[2] = acco[2] + ob[a * O_N + 2];
        }
    }
}

extern "C" void kernel_launch(void* const* d_in, const int* in_sizes, int n_in,
                              void* d_out, int out_size, void* d_ws, size_t ws_size,
                              hipStream_t stream) {
    const float* x   = (const float*)d_in[0];
    const float* inw = (const float*)d_in[1];
    const float* inb = (const float*)d_in[2];
    const float* w1  = (const float*)d_in[3];
    const float* b1  = (const float*)d_in[4];
    const float* w2  = (const float*)d_in[5];
    const float* b2  = (const float*)d_in[6];
    const float* w3  = (const float*)d_in[7];
    const float* b3  = (const float*)d_in[8];
    const float* ow  = (const float*)d_in[9];
    const float* ob  = (const float*)d_in[10];
    const float* s1w = (const float*)d_in[11];
    const float* s1b = (const float*)d_in[12];
    const float* s2w = (const float*)d_in[13];
    const float* s2b = (const float*)d_in[14];
    const float* hnw = (const float*)d_in[15];
    const float* hnb = (const float*)d_in[16];

    __bf16* ws = (__bf16*)d_ws;   // 17.7 MB of d_ws

    prep_kernel<<<dim3(1292), dim3(256), 0, stream>>>(w1, s1w, w2, s2w, w3, ow, ws);

    srek_mfma<<<dim3(A_N * (B_N / 64)), dim3(256), 0, stream>>>(
        x, inw, inb, b1, b2, b3, s1b, s2b, hnw, hnb, ob, ws, (float*)d_out);
}